// Round 5
// baseline (365.694 us; speedup 1.0000x reference)
//
#include <hip/hip_runtime.h>
#include <math.h>

// Problem constants
constexpr int B    = 8;
constexpr int T    = 2048;
constexpr int H    = 2048;
constexpr int NK   = 100000;
constexpr int PROJ = 512;
constexpr int TOPK = 10;
constexpr int TCHUNK = 64;
constexpr int TSUB   = T / TCHUNK;  // 32
constexpr int NCHUNK = 64;          // top-k stage-1 chunks per batch
constexpr int CS     = 1600;        // elements per chunk (64*1600 >= 100000)

#define NEG_INF -3.4e38f

// native vector type for nontemporal builtins (HIP float4 is a class type,
// which __builtin_nontemporal_load rejects)
typedef float vfloat4 __attribute__((ext_vector_type(4)));

// ---------------------------------------------------------------------------
// K1: partial sums over T-chunks for the query mean.  grid = 8*64*2 = 1024
__global__ void __launch_bounds__(256) k_partial_sum(const float* __restrict__ x,
                                                     float* __restrict__ partial) {
    int hblk = blockIdx.x & 1;
    int tc   = (blockIdx.x >> 1) & 63;
    int b    = blockIdx.x >> 7;
    int h    = hblk * 1024 + threadIdx.x * 4;
    const float* xp = x + ((size_t)b * T + (size_t)tc * TSUB) * H + h;
    vfloat4 acc = {0.f, 0.f, 0.f, 0.f};
#pragma unroll 4
    for (int t = 0; t < TSUB; ++t) {
        vfloat4 v = __builtin_nontemporal_load((const vfloat4*)(xp + (size_t)t * H));
        acc += v;
    }
    *(vfloat4*)(partial + ((size_t)(b * TCHUNK + tc)) * H + h) = acc;
}

// K2: finish mean -> query, also write first half of gate_input.  grid = 64
__global__ void __launch_bounds__(256) k_finish_mean(const float* __restrict__ partial,
                                                     float* __restrict__ query,
                                                     float* __restrict__ gi) {
    int idx = blockIdx.x * 256 + threadIdx.x;  // b*H + h
    int b = idx >> 11, h = idx & 2047;
    float s = 0.f;
    for (int tc = 0; tc < TCHUNK; ++tc)
        s += partial[((size_t)(b * TCHUNK + tc)) * H + h];
    float m = s * (1.0f / T);
    query[idx] = m;
    gi[(size_t)b * 2 * H + h] = m;
}

// K3: q = query @ Wq.T + bq.  One wave per (b,p).  grid = 8*512/4 = 1024
__global__ void __launch_bounds__(256) k_q(const float* __restrict__ query,
                                           const float* __restrict__ Wq,
                                           const float* __restrict__ bq,
                                           float* __restrict__ qv) {
    int wave = threadIdx.x >> 6, lane = threadIdx.x & 63;
    int gidx = blockIdx.x * 4 + wave;      // b*PROJ + p
    int b = gidx >> 9, p = gidx & 511;
    const float* qr = query + (size_t)b * H;
    const float* wr = Wq + (size_t)p * H;
    float acc = 0.f;
#pragma unroll
    for (int j = lane * 4; j < H; j += 256) {
        float4 a = *(const float4*)(qr + j);
        float4 w = *(const float4*)(wr + j);
        acc += a.x * w.x + a.y * w.y + a.z * w.z + a.w * w.w;
    }
    for (int o = 32; o > 0; o >>= 1) acc += __shfl_down(acc, o, 64);
    if (lane == 0) qv[gidx] = acc + bq[p];
}

// K4a: qk[b,h] = sum_p q[b,p] * Wk[p,h], partial over p-chunks of 32.
// grid = 129: blocks 0..127 do the partial GEMV (hblk(8) x pc(16));
// block 128 computes qb[b] = q[b].bk (folded-in former k_qb).
__global__ void __launch_bounds__(256) k_qk_partial(const float* __restrict__ qv,
                                                    const float* __restrict__ Wk,
                                                    const float* __restrict__ bk,
                                                    float* __restrict__ pqk,
                                                    float* __restrict__ qb) {
    if (blockIdx.x == 128) {
        int lane = threadIdx.x & 63;
        if (threadIdx.x < 64) {
            for (int b = 0; b < B; ++b) {
                float acc = 0.f;
                for (int j = lane; j < PROJ; j += 64) acc += qv[b * PROJ + j] * bk[j];
                for (int o = 32; o > 0; o >>= 1) acc += __shfl_down(acc, o, 64);
                if (lane == 0) qb[b] = acc;
            }
        }
        return;
    }
    int hblk = blockIdx.x & 7, pc = blockIdx.x >> 3;
    int h = hblk * 256 + threadIdx.x;
    float acc[B];
#pragma unroll
    for (int b = 0; b < B; ++b) acc[b] = 0.f;
    for (int p = pc * 32; p < pc * 32 + 32; ++p) {
        float w = Wk[(size_t)p * H + h];
#pragma unroll
        for (int b = 0; b < B; ++b) acc[b] += qv[b * PROJ + p] * w;
    }
#pragma unroll
    for (int b = 0; b < B; ++b)
        pqk[((size_t)(pc * B + b)) * H + h] = acc[b];
}

// K4b: reduce 16 p-chunks.  grid = 64
__global__ void __launch_bounds__(256) k_qk_finish(const float* __restrict__ pqk,
                                                   float* __restrict__ qk) {
    int idx = blockIdx.x * 256 + threadIdx.x;  // b*H + h
    int b = idx >> 11, h = idx & 2047;
    float s = 0.f;
#pragma unroll
    for (int pc = 0; pc < 16; ++pc) s += pqk[((size_t)(pc * B + b)) * H + h];
    qk[idx] = s;
}

// K5: the big streaming pass.  scores[b,n] = conf[n] * (keys[n].qk[b] + qb[b])
// block = 512 threads (8 waves), each wave does 4 rows -> 32 rows/block.
// grid = 100000/32 = 3125 exactly.
// NOTE: unroll capped at 4 (live kv = 16 float4 = 64 VGPR + 32 acc ~ fits
// under the 128-VGPR cap; full unroll spilled ~1 GB in round 1).
__global__ void __launch_bounds__(512) k_scores(const float* __restrict__ keys,
                                                const float* __restrict__ conf,
                                                const float* __restrict__ qk,
                                                const float* __restrict__ qb,
                                                float* __restrict__ scores) {
    __shared__ float sqk[B * H];  // 64 KB
    for (int i = threadIdx.x * 4; i < B * H; i += 2048)
        *(float4*)(sqk + i) = *(const float4*)(qk + i);
    __syncthreads();

    const int wave = threadIdx.x >> 6, lane = threadIdx.x & 63;
    const long r0 = (long)blockIdx.x * 32 + wave * 4;

    float acc[4][B];
#pragma unroll
    for (int r = 0; r < 4; ++r)
#pragma unroll
        for (int b = 0; b < B; ++b) acc[r][b] = 0.f;

#pragma unroll 4
    for (int it = 0; it < 8; ++it) {
        int j = it * 256 + lane * 4;
        vfloat4 kv[4];
#pragma unroll
        for (int r = 0; r < 4; ++r)
            kv[r] = __builtin_nontemporal_load(
                (const vfloat4*)(keys + (size_t)(r0 + r) * H + j));
#pragma unroll
        for (int b = 0; b < B; ++b) {
            float4 w = *(const float4*)(sqk + b * H + j);
#pragma unroll
            for (int r = 0; r < 4; ++r)
                acc[r][b] += kv[r].x * w.x + kv[r].y * w.y + kv[r].z * w.z + kv[r].w * w.w;
        }
    }

#pragma unroll
    for (int r = 0; r < 4; ++r) {
        long n = r0 + r;
#pragma unroll
        for (int b = 0; b < B; ++b) {
            float v = acc[r][b];
            for (int o = 32; o > 0; o >>= 1) v += __shfl_down(v, o, 64);
            if (lane == 0)
                scores[(size_t)b * NK + n] = conf[n] * (v + qb[b]);
        }
    }
}

// ---------------------------------------------------------------------------
// Top-k, two-stage.  Stage 1: grid = B*NCHUNK = 512 blocks x 256 threads.
// Each block -> top-10 of its 1600-element chunk via per-thread sorted top-10
// + per-wave shuffle argmax-consume + cross-wave merge (wave 0).
__global__ void __launch_bounds__(256) k_topk1(const float* __restrict__ scores,
                                               float* __restrict__ candv,
                                               int* __restrict__ candi) {
    const int c = blockIdx.x & (NCHUNK - 1), b = blockIdx.x >> 6;
    const int tid = threadIdx.x, lane = tid & 63, wave = tid >> 6;
    __shared__ float wv[4 * TOPK];
    __shared__ int   wi[4 * TOPK];

    float lv[TOPK];
    int   li[TOPK];
#pragma unroll
    for (int i = 0; i < TOPK; ++i) { lv[i] = NEG_INF; li[i] = 0; }

    const int start = c * CS;
    const int end = (start + CS < NK) ? start + CS : NK;
    for (int n = start + tid; n < end; n += 256) {
        float v = scores[(size_t)b * NK + n];
        if (v > lv[TOPK - 1]) {
            bool m[TOPK];
#pragma unroll
            for (int i = 0; i < TOPK; ++i) m[i] = (lv[i] < v);
#pragma unroll
            for (int i = TOPK - 1; i > 0; --i)
                if (m[i - 1]) { lv[i] = lv[i - 1]; li[i] = li[i - 1]; }
#pragma unroll
            for (int i = 0; i < TOPK; ++i)
                if (m[i] && (i == 0 || !m[i - 1])) { lv[i] = v; li[i] = n; }
        }
    }

    // per-wave argmax-consume: lists are sorted desc, so each lane proposes
    // its current head; winner advances its pointer.
    int ptr = 0;
    for (int round = 0; round < TOPK; ++round) {
        float bv = (ptr < TOPK) ? lv[ptr] : NEG_INF;
        int   bi = (ptr < TOPK) ? li[ptr] : 0;
        int   bl = lane;
        for (int o = 32; o > 0; o >>= 1) {
            float ov = __shfl_down(bv, o, 64);
            int   oi = __shfl_down(bi, o, 64);
            int   ol = __shfl_down(bl, o, 64);
            if (ov > bv) { bv = ov; bi = oi; bl = ol; }
        }
        if (lane == 0) { wv[wave * TOPK + round] = bv; wi[wave * TOPK + round] = bi; }
        bl = __shfl(bl, 0, 64);
        if (lane == bl) ptr++;
    }
    __syncthreads();

    // wave 0 merges the 4 waves' top-10 lists (40 candidates, 1 per lane)
    if (wave == 0) {
        float v = (lane < 4 * TOPK) ? wv[lane] : NEG_INF;
        int  id = (lane < 4 * TOPK) ? wi[lane] : 0;
        for (int round = 0; round < TOPK; ++round) {
            float bv = v; int bi = id; int bl = lane;
            for (int o = 32; o > 0; o >>= 1) {
                float ov = __shfl_down(bv, o, 64);
                int   oi = __shfl_down(bi, o, 64);
                int   ol = __shfl_down(bl, o, 64);
                if (ov > bv) { bv = ov; bi = oi; bl = ol; }
            }
            if (lane == 0) {
                candv[(size_t)(b * NCHUNK + c) * TOPK + round] = bv;
                candi[(size_t)(b * NCHUNK + c) * TOPK + round] = bi;
            }
            bl = __shfl(bl, 0, 64);
            if (lane == bl) v = NEG_INF;
        }
    }
}

// K7: stage-2 top-k merge (redundant per block, wave 0) + mem_summary ->
// second half of gate_input.  grid = 64 blocks x 256 threads.
__global__ void __launch_bounds__(256) k_memsum(const float* __restrict__ keys,
                                                const float* __restrict__ candv,
                                                const int* __restrict__ candi,
                                                float* __restrict__ gi) {
    const int blk = blockIdx.x;
    const int b = (blk * 256) >> 11;  // 8 consecutive blocks per batch
    const int tid = threadIdx.x, lane = tid & 63, wave = tid >> 6;
    __shared__ int stop[TOPK];

    // wave 0: merge the 640 stage-1 candidates (lane <-> chunk, sorted desc)
    if (wave == 0) {
        float lv[TOPK];
        int   li[TOPK];
#pragma unroll
        for (int r = 0; r < TOPK; ++r) {
            lv[r] = candv[(size_t)(b * NCHUNK + lane) * TOPK + r];
            li[r] = candi[(size_t)(b * NCHUNK + lane) * TOPK + r];
        }
        int ptr = 0;
        for (int round = 0; round < TOPK; ++round) {
            float bv = (ptr < TOPK) ? lv[ptr] : NEG_INF;
            int   bi = (ptr < TOPK) ? li[ptr] : 0;
            int   bl = lane;
            for (int o = 32; o > 0; o >>= 1) {
                float ov = __shfl_down(bv, o, 64);
                int   oi = __shfl_down(bi, o, 64);
                int   ol = __shfl_down(bl, o, 64);
                if (ov > bv) { bv = ov; bi = oi; bl = ol; }
            }
            if (lane == 0) stop[round] = bi;
            bl = __shfl(bl, 0, 64);
            if (lane == bl) ptr++;
        }
    }
    __syncthreads();

    int h = (blk * 256 + tid) & 2047;
    float s = 0.f;
#pragma unroll
    for (int i = 0; i < TOPK; ++i) {
        int n = stop[i];
        s += keys[(size_t)n * H + h];
    }
    gi[(size_t)b * 2 * H + H + h] = s * (1.0f / TOPK);
}

// K8: gate = sigmoid(gi @ Wg.T + bg), h1 = gelu(gi @ Wm1.T + bm1)
// One wave per output row across both matrices (rows 0..2047 -> gate,
// 2048..4095 -> h1), all 8 batches per wave.  grid = 4096/4 = 1024
__global__ void __launch_bounds__(256) k_mlp1(const float* __restrict__ gi,
                                              const float* __restrict__ Wg,
                                              const float* __restrict__ bg,
                                              const float* __restrict__ Wm1,
                                              const float* __restrict__ bm1,
                                              float* __restrict__ gate,
                                              float* __restrict__ h1) {
    int wave = threadIdx.x >> 6, lane = threadIdx.x & 63;
    int row = blockIdx.x * 4 + wave;  // 0..4095
    bool isGate = row < H;
    int i = isGate ? row : row - H;
    const float* W = (isGate ? Wg : Wm1) + (size_t)i * 2 * H;

    float acc[B];
#pragma unroll
    for (int b = 0; b < B; ++b) acc[b] = 0.f;

#pragma unroll
    for (int j = lane * 4; j < 2 * H; j += 256) {
        float4 w = *(const float4*)(W + j);
#pragma unroll
        for (int b = 0; b < B; ++b) {
            float4 g = *(const float4*)(gi + (size_t)b * 2 * H + j);
            acc[b] += w.x * g.x + w.y * g.y + w.z * g.z + w.w * g.w;
        }
    }
#pragma unroll
    for (int b = 0; b < B; ++b) {
        float v = acc[b];
        for (int o = 32; o > 0; o >>= 1) v += __shfl_down(v, o, 64);
        if (lane == 0) {
            if (isGate) {
                v += bg[i];
                gate[b * H + i] = 1.0f / (1.0f + expf(-v));
            } else {
                v += bm1[i];
                h1[b * H + i] = 0.5f * v * (1.0f + erff(v * 0.70710678118654752f));
            }
        }
    }
}

// K9: mem_integrated = h1 @ Wm2.T + bm2; gm = gate * mem_integrated.
// grid = 2048/4 = 512
__global__ void __launch_bounds__(256) k_mlp2(const float* __restrict__ h1,
                                              const float* __restrict__ Wm2,
                                              const float* __restrict__ bm2,
                                              const float* __restrict__ gate,
                                              float* __restrict__ gm) {
    int wave = threadIdx.x >> 6, lane = threadIdx.x & 63;
    int o = blockIdx.x * 4 + wave;  // 0..2047
    const float* W = Wm2 + (size_t)o * H;
    float acc[B];
#pragma unroll
    for (int b = 0; b < B; ++b) acc[b] = 0.f;
#pragma unroll
    for (int j = lane * 4; j < H; j += 256) {
        float4 w = *(const float4*)(W + j);
#pragma unroll
        for (int b = 0; b < B; ++b) {
            float4 hh = *(const float4*)(h1 + (size_t)b * H + j);
            acc[b] += w.x * hh.x + w.y * hh.y + w.z * hh.z + w.w * hh.w;
        }
    }
#pragma unroll
    for (int b = 0; b < B; ++b) {
        float v = acc[b];
        for (int oo = 32; oo > 0; oo >>= 1) v += __shfl_down(v, oo, 64);
        if (lane == 0) gm[b * H + o] = gate[b * H + o] * (v + bm2[o]);
    }
}

// K10: y = x + gm (broadcast over T), LayerNorm over H.
// One wave per row, whole row in registers, xor-butterfly reductions:
// zero barriers, zero LDS.  grid = B*T/4 = 4096, block = 256.
__global__ void __launch_bounds__(256) k_final(const float* __restrict__ x,
                                               const float* __restrict__ gm,
                                               const float* __restrict__ gamma,
                                               const float* __restrict__ beta,
                                               float* __restrict__ out) {
    const int lane = threadIdx.x & 63, wave = threadIdx.x >> 6;
    const size_t row = (size_t)blockIdx.x * 4 + wave;
    const int b = (int)(row >> 11);  // T = 2048
    const float* xr  = x + row * H;
    const float* gmr = gm + (size_t)b * H;

    vfloat4 y[8];
    float s = 0.f;
#pragma unroll
    for (int it = 0; it < 8; ++it) {
        int j = it * 256 + lane * 4;
        vfloat4 xv = __builtin_nontemporal_load((const vfloat4*)(xr + j));
        vfloat4 gv = *(const vfloat4*)(gmr + j);
        y[it] = xv + gv;
        s += y[it].x + y[it].y + y[it].z + y[it].w;
    }
#pragma unroll
    for (int o = 32; o > 0; o >>= 1) s += __shfl_xor(s, o, 64);
    const float mu = s * (1.0f / H);

    float s2 = 0.f;
#pragma unroll
    for (int it = 0; it < 8; ++it) {
        vfloat4 d = y[it] - mu;
        y[it] = d;
        s2 += d.x * d.x + d.y * d.y + d.z * d.z + d.w * d.w;
    }
#pragma unroll
    for (int o = 32; o > 0; o >>= 1) s2 += __shfl_xor(s2, o, 64);
    const float inv = rsqrtf(s2 * (1.0f / H) + 1e-5f);

#pragma unroll
    for (int it = 0; it < 8; ++it) {
        int j = it * 256 + lane * 4;
        vfloat4 g = *(const vfloat4*)(gamma + j);
        vfloat4 bb = *(const vfloat4*)(beta + j);
        vfloat4 o_ = y[it] * inv * g + bb;
        __builtin_nontemporal_store(o_, (vfloat4*)(out + row * H + j));
    }
}

// ---------------------------------------------------------------------------
extern "C" void kernel_launch(void* const* d_in, const int* in_sizes, int n_in,
                              void* d_out, int out_size, void* d_ws, size_t ws_size,
                              hipStream_t stream) {
    const float* x     = (const float*)d_in[0];
    const float* keys  = (const float*)d_in[1];
    const float* conf  = (const float*)d_in[2];
    const float* Wq    = (const float*)d_in[3];
    const float* bq    = (const float*)d_in[4];
    const float* Wk    = (const float*)d_in[5];
    const float* bk    = (const float*)d_in[6];
    const float* Wg    = (const float*)d_in[7];
    const float* bg    = (const float*)d_in[8];
    const float* Wm1   = (const float*)d_in[9];
    const float* bm1   = (const float*)d_in[10];
    const float* Wm2   = (const float*)d_in[11];
    const float* bm2   = (const float*)d_in[12];
    const float* gamma = (const float*)d_in[13];
    const float* beta  = (const float*)d_in[14];
    float* out = (float*)d_out;

    float* ws = (float*)d_ws;
    float* partial = ws;        ws += (size_t)B * TCHUNK * H;  // 1M floats
    float* query   = ws;        ws += B * H;
    float* gi      = ws;        ws += B * 2 * H;
    float* qv      = ws;        ws += B * PROJ;
    float* qb      = ws;        ws += 64;
    float* pqk     = ws;        ws += 16 * B * H;
    float* qk      = ws;        ws += B * H;
    float* scores  = ws;        ws += (size_t)B * NK;          // 800000
    float* candv   = ws;        ws += B * NCHUNK * TOPK;       // 5120
    int*   candi   = (int*)ws;  ws += B * NCHUNK * TOPK;       // 5120
    float* gate    = ws;        ws += B * H;
    float* h1      = ws;        ws += B * H;
    float* gm      = ws;        ws += B * H;

    k_partial_sum<<<B * TCHUNK * 2, 256, 0, stream>>>(x, partial);
    k_finish_mean<<<B * H / 256, 256, 0, stream>>>(partial, query, gi);
    k_q<<<B * PROJ / 4, 256, 0, stream>>>(query, Wq, bq, qv);
    k_qk_partial<<<129, 256, 0, stream>>>(qv, Wk, bk, pqk, qb);
    k_qk_finish<<<B * H / 256, 256, 0, stream>>>(pqk, qk);
    k_scores<<<NK / 32, 512, 0, stream>>>(keys, conf, qk, qb, scores);
    k_topk1<<<B * NCHUNK, 256, 0, stream>>>(scores, candv, candi);
    k_memsum<<<B * H / 256, 256, 0, stream>>>(keys, candv, candi, gi);
    k_mlp1<<<2 * H / 4, 256, 0, stream>>>(gi, Wg, bg, Wm1, bm1, gate, h1);
    k_mlp2<<<H / 4, 256, 0, stream>>>(h1, Wm2, bm2, gate, gm);
    k_final<<<B * T / 4, 256, 0, stream>>>(x, gm, gamma, beta, out);
}

// Round 6
// 349.356 us; speedup vs baseline: 1.0468x; 1.0468x over previous
//
#include <hip/hip_runtime.h>
#include <math.h>

// Problem constants
constexpr int B    = 8;
constexpr int T    = 2048;
constexpr int H    = 2048;
constexpr int NK   = 100000;
constexpr int PROJ = 512;
constexpr int TOPK = 10;
constexpr int TCHUNK = 64;
constexpr int TSUB   = T / TCHUNK;  // 32
constexpr int NCHUNK = 64;          // top-k stage-1 chunks per batch
constexpr int CS     = 1600;        // elements per chunk (64*1600 >= 100000)

#define NEG_INF -3.4e38f

// native vector types (HIP float4 is a class type, which the nontemporal
// builtins reject; ext vectors also give clang a shot at v_pk_fma_f32)
typedef float vfloat4 __attribute__((ext_vector_type(4)));
typedef float vfloat2 __attribute__((ext_vector_type(2)));

// ---------------------------------------------------------------------------
// K1: partial sums over T-chunks for the query mean.  grid = 8*64*2 = 1024
// x loads are CACHED (not NT): x (128 MB) fits Infinity Cache and is re-read
// by k_final.
__global__ void __launch_bounds__(256) k_partial_sum(const float* __restrict__ x,
                                                     float* __restrict__ partial) {
    int hblk = blockIdx.x & 1;
    int tc   = (blockIdx.x >> 1) & 63;
    int b    = blockIdx.x >> 7;
    int h    = hblk * 1024 + threadIdx.x * 4;
    const float* xp = x + ((size_t)b * T + (size_t)tc * TSUB) * H + h;
    vfloat4 acc = {0.f, 0.f, 0.f, 0.f};
#pragma unroll 4
    for (int t = 0; t < TSUB; ++t) {
        vfloat4 v = *(const vfloat4*)(xp + (size_t)t * H);
        acc += v;
    }
    *(vfloat4*)(partial + ((size_t)(b * TCHUNK + tc)) * H + h) = acc;
}

// K2: finish mean -> query, also write first half of gate_input.  grid = 64
__global__ void __launch_bounds__(256) k_finish_mean(const float* __restrict__ partial,
                                                     float* __restrict__ query,
                                                     float* __restrict__ gi) {
    int idx = blockIdx.x * 256 + threadIdx.x;  // b*H + h
    int b = idx >> 11, h = idx & 2047;
    float s = 0.f;
    for (int tc = 0; tc < TCHUNK; ++tc)
        s += partial[((size_t)(b * TCHUNK + tc)) * H + h];
    float m = s * (1.0f / T);
    query[idx] = m;
    gi[(size_t)b * 2 * H + h] = m;
}

// K3: q = query @ Wq.T + bq.  One wave per (b,p).  grid = 8*512/4 = 1024
__global__ void __launch_bounds__(256) k_q(const float* __restrict__ query,
                                           const float* __restrict__ Wq,
                                           const float* __restrict__ bq,
                                           float* __restrict__ qv) {
    int wave = threadIdx.x >> 6, lane = threadIdx.x & 63;
    int gidx = blockIdx.x * 4 + wave;      // b*PROJ + p
    int b = gidx >> 9, p = gidx & 511;
    const float* qr = query + (size_t)b * H;
    const float* wr = Wq + (size_t)p * H;
    float acc = 0.f;
#pragma unroll
    for (int j = lane * 4; j < H; j += 256) {
        float4 a = *(const float4*)(qr + j);
        float4 w = *(const float4*)(wr + j);
        acc += a.x * w.x + a.y * w.y + a.z * w.z + a.w * w.w;
    }
    for (int o = 32; o > 0; o >>= 1) acc += __shfl_down(acc, o, 64);
    if (lane == 0) qv[gidx] = acc + bq[p];
}

// K4a: qk[b,h] = sum_p q[b,p] * Wk[p,h], partial over p-chunks of 32.
// grid = 129: blocks 0..127 do the partial GEMV (hblk(8) x pc(16));
// block 128 computes qb[b] = q[b].bk (folded-in former k_qb).
__global__ void __launch_bounds__(256) k_qk_partial(const float* __restrict__ qv,
                                                    const float* __restrict__ Wk,
                                                    const float* __restrict__ bk,
                                                    float* __restrict__ pqk,
                                                    float* __restrict__ qb) {
    if (blockIdx.x == 128) {
        int lane = threadIdx.x & 63;
        if (threadIdx.x < 64) {
            for (int b = 0; b < B; ++b) {
                float acc = 0.f;
                for (int j = lane; j < PROJ; j += 64) acc += qv[b * PROJ + j] * bk[j];
                for (int o = 32; o > 0; o >>= 1) acc += __shfl_down(acc, o, 64);
                if (lane == 0) qb[b] = acc;
            }
        }
        return;
    }
    int hblk = blockIdx.x & 7, pc = blockIdx.x >> 3;
    int h = hblk * 256 + threadIdx.x;
    float acc[B];
#pragma unroll
    for (int b = 0; b < B; ++b) acc[b] = 0.f;
    for (int p = pc * 32; p < pc * 32 + 32; ++p) {
        float w = Wk[(size_t)p * H + h];
#pragma unroll
        for (int b = 0; b < B; ++b) acc[b] += qv[b * PROJ + p] * w;
    }
#pragma unroll
    for (int b = 0; b < B; ++b)
        pqk[((size_t)(pc * B + b)) * H + h] = acc[b];
}

// K4b: reduce 16 p-chunks.  grid = 64
__global__ void __launch_bounds__(256) k_qk_finish(const float* __restrict__ pqk,
                                                   float* __restrict__ qk) {
    int idx = blockIdx.x * 256 + threadIdx.x;  // b*H + h
    int b = idx >> 11, h = idx & 2047;
    float s = 0.f;
#pragma unroll
    for (int pc = 0; pc < 16; ++pc) s += pqk[((size_t)(pc * B + b)) * H + h];
    qk[idx] = s;
}

// K5: the big streaming pass.  scores[b,n] = conf[n] * (keys[n].qk[b] + qb[b])
// block = 512 threads (8 waves), each wave does 4 rows -> 32 rows/block.
// grid = 100000/32 = 3125 exactly.
// vfloat2 accumulators -> v_pk_fma_f32 (2 FMA/inst) halves VALU issue
// pressure; unroll capped at 2 (full unroll spilled ~1 GB in round 1).
__global__ void __launch_bounds__(512) k_scores(const float* __restrict__ keys,
                                                const float* __restrict__ conf,
                                                const float* __restrict__ qk,
                                                const float* __restrict__ qb,
                                                float* __restrict__ scores) {
    __shared__ float sqk[B * H];  // 64 KB
    for (int i = threadIdx.x * 4; i < B * H; i += 2048)
        *(vfloat4*)(sqk + i) = *(const vfloat4*)(qk + i);
    __syncthreads();

    const int wave = threadIdx.x >> 6, lane = threadIdx.x & 63;
    const long r0 = (long)blockIdx.x * 32 + wave * 4;

    vfloat2 acc[4][B];
#pragma unroll
    for (int r = 0; r < 4; ++r)
#pragma unroll
        for (int b = 0; b < B; ++b) acc[r][b] = (vfloat2){0.f, 0.f};

#pragma unroll 2
    for (int it = 0; it < 8; ++it) {
        int j = it * 256 + lane * 4;
        vfloat4 kv[4];
#pragma unroll
        for (int r = 0; r < 4; ++r)
            kv[r] = __builtin_nontemporal_load(
                (const vfloat4*)(keys + (size_t)(r0 + r) * H + j));
#pragma unroll
        for (int b = 0; b < B; ++b) {
            vfloat4 w = *(const vfloat4*)(sqk + b * H + j);
            vfloat2 wlo = w.xy, whi = w.zw;
#pragma unroll
            for (int r = 0; r < 4; ++r) {
                acc[r][b] += kv[r].xy * wlo;
                acc[r][b] += kv[r].zw * whi;
            }
        }
    }

#pragma unroll
    for (int r = 0; r < 4; ++r) {
        long n = r0 + r;
#pragma unroll
        for (int b = 0; b < B; ++b) {
            float v = acc[r][b].x + acc[r][b].y;
            for (int o = 32; o > 0; o >>= 1) v += __shfl_down(v, o, 64);
            if (lane == 0)
                scores[(size_t)b * NK + n] = conf[n] * (v + qb[b]);
        }
    }
}

// ---------------------------------------------------------------------------
// Top-k, two-stage.  Stage 1: grid = B*NCHUNK = 512 blocks x 256 threads.
// Each block -> top-10 of its 1600-element chunk via per-thread sorted top-10
// + per-wave shuffle argmax-consume + cross-wave merge (wave 0).
__global__ void __launch_bounds__(256) k_topk1(const float* __restrict__ scores,
                                               float* __restrict__ candv,
                                               int* __restrict__ candi) {
    const int c = blockIdx.x & (NCHUNK - 1), b = blockIdx.x >> 6;
    const int tid = threadIdx.x, lane = tid & 63, wave = tid >> 6;
    __shared__ float wv[4 * TOPK];
    __shared__ int   wi[4 * TOPK];

    float lv[TOPK];
    int   li[TOPK];
#pragma unroll
    for (int i = 0; i < TOPK; ++i) { lv[i] = NEG_INF; li[i] = 0; }

    const int start = c * CS;
    const int end = (start + CS < NK) ? start + CS : NK;
    for (int n = start + tid; n < end; n += 256) {
        float v = scores[(size_t)b * NK + n];
        if (v > lv[TOPK - 1]) {
            bool m[TOPK];
#pragma unroll
            for (int i = 0; i < TOPK; ++i) m[i] = (lv[i] < v);
#pragma unroll
            for (int i = TOPK - 1; i > 0; --i)
                if (m[i - 1]) { lv[i] = lv[i - 1]; li[i] = li[i - 1]; }
#pragma unroll
            for (int i = 0; i < TOPK; ++i)
                if (m[i] && (i == 0 || !m[i - 1])) { lv[i] = v; li[i] = n; }
        }
    }

    // per-wave argmax-consume: lists are sorted desc, so each lane proposes
    // its current head; winner advances its pointer.
    int ptr = 0;
    for (int round = 0; round < TOPK; ++round) {
        float bv = (ptr < TOPK) ? lv[ptr] : NEG_INF;
        int   bi = (ptr < TOPK) ? li[ptr] : 0;
        int   bl = lane;
        for (int o = 32; o > 0; o >>= 1) {
            float ov = __shfl_down(bv, o, 64);
            int   oi = __shfl_down(bi, o, 64);
            int   ol = __shfl_down(bl, o, 64);
            if (ov > bv) { bv = ov; bi = oi; bl = ol; }
        }
        if (lane == 0) { wv[wave * TOPK + round] = bv; wi[wave * TOPK + round] = bi; }
        bl = __shfl(bl, 0, 64);
        if (lane == bl) ptr++;
    }
    __syncthreads();

    // wave 0 merges the 4 waves' top-10 lists (40 candidates, 1 per lane)
    if (wave == 0) {
        float v = (lane < 4 * TOPK) ? wv[lane] : NEG_INF;
        int  id = (lane < 4 * TOPK) ? wi[lane] : 0;
        for (int round = 0; round < TOPK; ++round) {
            float bv = v; int bi = id; int bl = lane;
            for (int o = 32; o > 0; o >>= 1) {
                float ov = __shfl_down(bv, o, 64);
                int   oi = __shfl_down(bi, o, 64);
                int   ol = __shfl_down(bl, o, 64);
                if (ov > bv) { bv = ov; bi = oi; bl = ol; }
            }
            if (lane == 0) {
                candv[(size_t)(b * NCHUNK + c) * TOPK + round] = bv;
                candi[(size_t)(b * NCHUNK + c) * TOPK + round] = bi;
            }
            bl = __shfl(bl, 0, 64);
            if (lane == bl) v = NEG_INF;
        }
    }
}

// K7: stage-2 top-k merge (redundant per block, wave 0) + mem_summary ->
// second half of gate_input.  grid = 64 blocks x 256 threads.
__global__ void __launch_bounds__(256) k_memsum(const float* __restrict__ keys,
                                                const float* __restrict__ candv,
                                                const int* __restrict__ candi,
                                                float* __restrict__ gi) {
    const int blk = blockIdx.x;
    const int b = (blk * 256) >> 11;  // 8 consecutive blocks per batch
    const int tid = threadIdx.x, lane = tid & 63, wave = tid >> 6;
    __shared__ int stop[TOPK];

    // wave 0: merge the 640 stage-1 candidates (lane <-> chunk, sorted desc)
    if (wave == 0) {
        float lv[TOPK];
        int   li[TOPK];
#pragma unroll
        for (int r = 0; r < TOPK; ++r) {
            lv[r] = candv[(size_t)(b * NCHUNK + lane) * TOPK + r];
            li[r] = candi[(size_t)(b * NCHUNK + lane) * TOPK + r];
        }
        int ptr = 0;
        for (int round = 0; round < TOPK; ++round) {
            float bv = (ptr < TOPK) ? lv[ptr] : NEG_INF;
            int   bi = (ptr < TOPK) ? li[ptr] : 0;
            int   bl = lane;
            for (int o = 32; o > 0; o >>= 1) {
                float ov = __shfl_down(bv, o, 64);
                int   oi = __shfl_down(bi, o, 64);
                int   ol = __shfl_down(bl, o, 64);
                if (ov > bv) { bv = ov; bi = oi; bl = ol; }
            }
            if (lane == 0) stop[round] = bi;
            bl = __shfl(bl, 0, 64);
            if (lane == bl) ptr++;
        }
    }
    __syncthreads();

    int h = (blk * 256 + tid) & 2047;
    float s = 0.f;
#pragma unroll
    for (int i = 0; i < TOPK; ++i) {
        int n = stop[i];
        s += keys[(size_t)n * H + h];
    }
    gi[(size_t)b * 2 * H + H + h] = s * (1.0f / TOPK);
}

// K8: gate = sigmoid(gi @ Wg.T + bg), h1 = gelu(gi @ Wm1.T + bm1)
// One wave per output row across both matrices (rows 0..2047 -> gate,
// 2048..4095 -> h1), all 8 batches per wave.  grid = 4096/4 = 1024
__global__ void __launch_bounds__(256) k_mlp1(const float* __restrict__ gi,
                                              const float* __restrict__ Wg,
                                              const float* __restrict__ bg,
                                              const float* __restrict__ Wm1,
                                              const float* __restrict__ bm1,
                                              float* __restrict__ gate,
                                              float* __restrict__ h1) {
    int wave = threadIdx.x >> 6, lane = threadIdx.x & 63;
    int row = blockIdx.x * 4 + wave;  // 0..4095
    bool isGate = row < H;
    int i = isGate ? row : row - H;
    const float* W = (isGate ? Wg : Wm1) + (size_t)i * 2 * H;

    float acc[B];
#pragma unroll
    for (int b = 0; b < B; ++b) acc[b] = 0.f;

#pragma unroll
    for (int j = lane * 4; j < 2 * H; j += 256) {
        float4 w = *(const float4*)(W + j);
#pragma unroll
        for (int b = 0; b < B; ++b) {
            float4 g = *(const float4*)(gi + (size_t)b * 2 * H + j);
            acc[b] += w.x * g.x + w.y * g.y + w.z * g.z + w.w * g.w;
        }
    }
#pragma unroll
    for (int b = 0; b < B; ++b) {
        float v = acc[b];
        for (int o = 32; o > 0; o >>= 1) v += __shfl_down(v, o, 64);
        if (lane == 0) {
            if (isGate) {
                v += bg[i];
                gate[b * H + i] = 1.0f / (1.0f + expf(-v));
            } else {
                v += bm1[i];
                h1[b * H + i] = 0.5f * v * (1.0f + erff(v * 0.70710678118654752f));
            }
        }
    }
}

// K9: mem_integrated = h1 @ Wm2.T + bm2; gm = gate * mem_integrated.
// grid = 2048/4 = 512
__global__ void __launch_bounds__(256) k_mlp2(const float* __restrict__ h1,
                                              const float* __restrict__ Wm2,
                                              const float* __restrict__ bm2,
                                              const float* __restrict__ gate,
                                              float* __restrict__ gm) {
    int wave = threadIdx.x >> 6, lane = threadIdx.x & 63;
    int o = blockIdx.x * 4 + wave;  // 0..2047
    const float* W = Wm2 + (size_t)o * H;
    float acc[B];
#pragma unroll
    for (int b = 0; b < B; ++b) acc[b] = 0.f;
#pragma unroll
    for (int j = lane * 4; j < H; j += 256) {
        float4 w = *(const float4*)(W + j);
#pragma unroll
        for (int b = 0; b < B; ++b) {
            float4 hh = *(const float4*)(h1 + (size_t)b * H + j);
            acc[b] += w.x * hh.x + w.y * hh.y + w.z * hh.z + w.w * hh.w;
        }
    }
#pragma unroll
    for (int b = 0; b < B; ++b) {
        float v = acc[b];
        for (int oo = 32; oo > 0; oo >>= 1) v += __shfl_down(v, oo, 64);
        if (lane == 0) gm[b * H + o] = gate[b * H + o] * (v + bm2[o]);
    }
}

// K10: y = x + gm (broadcast over T), LayerNorm over H.
// One wave per row, whole row in registers, xor-butterfly reductions:
// zero barriers, zero LDS.  x read is cached (should hit L3, warmed by K1).
// grid = B*T/4 = 4096, block = 256.
__global__ void __launch_bounds__(256) k_final(const float* __restrict__ x,
                                               const float* __restrict__ gm,
                                               const float* __restrict__ gamma,
                                               const float* __restrict__ beta,
                                               float* __restrict__ out) {
    const int lane = threadIdx.x & 63, wave = threadIdx.x >> 6;
    const size_t row = (size_t)blockIdx.x * 4 + wave;
    const int b = (int)(row >> 11);  // T = 2048
    const float* xr  = x + row * H;
    const float* gmr = gm + (size_t)b * H;

    vfloat4 y[8];
    float s = 0.f;
#pragma unroll
    for (int it = 0; it < 8; ++it) {
        int j = it * 256 + lane * 4;
        vfloat4 xv = *(const vfloat4*)(xr + j);
        vfloat4 gv = *(const vfloat4*)(gmr + j);
        y[it] = xv + gv;
        s += y[it].x + y[it].y + y[it].z + y[it].w;
    }
#pragma unroll
    for (int o = 32; o > 0; o >>= 1) s += __shfl_xor(s, o, 64);
    const float mu = s * (1.0f / H);

    float s2 = 0.f;
#pragma unroll
    for (int it = 0; it < 8; ++it) {
        vfloat4 d = y[it] - mu;
        y[it] = d;
        s2 += d.x * d.x + d.y * d.y + d.z * d.z + d.w * d.w;
    }
#pragma unroll
    for (int o = 32; o > 0; o >>= 1) s2 += __shfl_xor(s2, o, 64);
    const float inv = rsqrtf(s2 * (1.0f / H) + 1e-5f);

#pragma unroll
    for (int it = 0; it < 8; ++it) {
        int j = it * 256 + lane * 4;
        vfloat4 g = *(const vfloat4*)(gamma + j);
        vfloat4 bb = *(const vfloat4*)(beta + j);
        vfloat4 o_ = y[it] * inv * g + bb;
        __builtin_nontemporal_store(o_, (vfloat4*)(out + row * H + j));
    }
}

// ---------------------------------------------------------------------------
extern "C" void kernel_launch(void* const* d_in, const int* in_sizes, int n_in,
                              void* d_out, int out_size, void* d_ws, size_t ws_size,
                              hipStream_t stream) {
    const float* x     = (const float*)d_in[0];
    const float* keys  = (const float*)d_in[1];
    const float* conf  = (const float*)d_in[2];
    const float* Wq    = (const float*)d_in[3];
    const float* bq    = (const float*)d_in[4];
    const float* Wk    = (const float*)d_in[5];
    const float* bk    = (const float*)d_in[6];
    const float* Wg    = (const float*)d_in[7];
    const float* bg    = (const float*)d_in[8];
    const float* Wm1   = (const float*)d_in[9];
    const float* bm1   = (const float*)d_in[10];
    const float* Wm2   = (const float*)d_in[11];
    const float* bm2   = (const float*)d_in[12];
    const float* gamma = (const float*)d_in[13];
    const float* beta  = (const float*)d_in[14];
    float* out = (float*)d_out;

    float* ws = (float*)d_ws;
    float* partial = ws;        ws += (size_t)B * TCHUNK * H;  // 1M floats
    float* query   = ws;        ws += B * H;
    float* gi      = ws;        ws += B * 2 * H;
    float* qv      = ws;        ws += B * PROJ;
    float* qb      = ws;        ws += 64;
    float* pqk     = ws;        ws += 16 * B * H;
    float* qk      = ws;        ws += B * H;
    float* scores  = ws;        ws += (size_t)B * NK;          // 800000
    float* candv   = ws;        ws += B * NCHUNK * TOPK;       // 5120
    int*   candi   = (int*)ws;  ws += B * NCHUNK * TOPK;       // 5120
    float* gate    = ws;        ws += B * H;
    float* h1      = ws;        ws += B * H;
    float* gm      = ws;        ws += B * H;

    k_partial_sum<<<B * TCHUNK * 2, 256, 0, stream>>>(x, partial);
    k_finish_mean<<<B * H / 256, 256, 0, stream>>>(partial, query, gi);
    k_q<<<B * PROJ / 4, 256, 0, stream>>>(query, Wq, bq, qv);
    k_qk_partial<<<129, 256, 0, stream>>>(qv, Wk, bk, pqk, qb);
    k_qk_finish<<<B * H / 256, 256, 0, stream>>>(pqk, qk);
    k_scores<<<NK / 32, 512, 0, stream>>>(keys, conf, qk, qb, scores);
    k_topk1<<<B * NCHUNK, 256, 0, stream>>>(scores, candv, candi);
    k_memsum<<<B * H / 256, 256, 0, stream>>>(keys, candv, candi, gi);
    k_mlp1<<<2 * H / 4, 256, 0, stream>>>(gi, Wg, bg, Wm1, bm1, gate, h1);
    k_mlp2<<<H / 4, 256, 0, stream>>>(h1, Wm2, bm2, gate, gm);
    k_final<<<B * T / 4, 256, 0, stream>>>(x, gm, gamma, beta, out);
}

// Round 8
// 349.189 us; speedup vs baseline: 1.0473x; 1.0005x over previous
//
#include <hip/hip_runtime.h>
#include <math.h>

// Problem constants
constexpr int B    = 8;
constexpr int T    = 2048;
constexpr int H    = 2048;
constexpr int NK   = 100000;
constexpr int PROJ = 512;
constexpr int TOPK = 10;
constexpr int TCHUNK = 64;
constexpr int TSUB   = T / TCHUNK;  // 32
constexpr int NCHUNK = 64;          // top-k stage-1 chunks per batch
constexpr int CS     = 1600;        // elements per chunk (64*1600 >= 100000)

#define NEG_INF -3.4e38f

// native vector types (HIP float4 is a class type, which the nontemporal
// builtins reject; ext vectors also give clang a shot at v_pk_fma_f32)
typedef float vfloat4 __attribute__((ext_vector_type(4)));
typedef float vfloat2 __attribute__((ext_vector_type(2)));

// ---------------------------------------------------------------------------
// K1: partial sums over T-chunks for the query mean.  grid = 8*64*2 = 1024
// x loads are CACHED (not NT): x (128 MB) fits Infinity Cache and is re-read
// by k_final.
__global__ void __launch_bounds__(256) k_partial_sum(const float* __restrict__ x,
                                                     float* __restrict__ partial) {
    int hblk = blockIdx.x & 1;
    int tc   = (blockIdx.x >> 1) & 63;
    int b    = blockIdx.x >> 7;
    int h    = hblk * 1024 + threadIdx.x * 4;
    const float* xp = x + ((size_t)b * T + (size_t)tc * TSUB) * H + h;
    vfloat4 acc = {0.f, 0.f, 0.f, 0.f};
#pragma unroll 4
    for (int t = 0; t < TSUB; ++t) {
        vfloat4 v = *(const vfloat4*)(xp + (size_t)t * H);
        acc += v;
    }
    *(vfloat4*)(partial + ((size_t)(b * TCHUNK + tc)) * H + h) = acc;
}

// K2: finish mean -> query, also write first half of gate_input.  grid = 64
__global__ void __launch_bounds__(256) k_finish_mean(const float* __restrict__ partial,
                                                     float* __restrict__ query,
                                                     float* __restrict__ gi) {
    int idx = blockIdx.x * 256 + threadIdx.x;  // b*H + h
    int b = idx >> 11, h = idx & 2047;
    float s = 0.f;
#pragma unroll 8
    for (int tc = 0; tc < TCHUNK; ++tc)
        s += partial[((size_t)(b * TCHUNK + tc)) * H + h];
    float m = s * (1.0f / T);
    query[idx] = m;
    gi[(size_t)b * 2 * H + h] = m;
}

// K3: q = query @ Wq.T + bq.  One wave per (b,p).  grid = 8*512/4 = 1024
__global__ void __launch_bounds__(256) k_q(const float* __restrict__ query,
                                           const float* __restrict__ Wq,
                                           const float* __restrict__ bq,
                                           float* __restrict__ qv) {
    int wave = threadIdx.x >> 6, lane = threadIdx.x & 63;
    int gidx = blockIdx.x * 4 + wave;      // b*PROJ + p
    int b = gidx >> 9, p = gidx & 511;
    const float* qr = query + (size_t)b * H;
    const float* wr = Wq + (size_t)p * H;
    float acc = 0.f;
#pragma unroll 2
    for (int j = lane * 4; j < H; j += 256) {
        float4 a = *(const float4*)(qr + j);
        float4 w = *(const float4*)(wr + j);
        acc += a.x * w.x + a.y * w.y + a.z * w.z + a.w * w.w;
    }
    for (int o = 32; o > 0; o >>= 1) acc += __shfl_down(acc, o, 64);
    if (lane == 0) qv[gidx] = acc + bq[p];
}

// K4a: qk[b,h] = sum_p q[b,p] * Wk[p,h], partial over p-chunks of 32.
// grid = 129: blocks 0..127 do the partial GEMV (hblk(8) x pc(16));
// block 128 computes qb[b] = q[b].bk (folded-in former k_qb).
__global__ void __launch_bounds__(256) k_qk_partial(const float* __restrict__ qv,
                                                    const float* __restrict__ Wk,
                                                    const float* __restrict__ bk,
                                                    float* __restrict__ pqk,
                                                    float* __restrict__ qb) {
    if (blockIdx.x == 128) {
        int lane = threadIdx.x & 63;
        if (threadIdx.x < 64) {
            for (int b = 0; b < B; ++b) {
                float acc = 0.f;
                for (int j = lane; j < PROJ; j += 64) acc += qv[b * PROJ + j] * bk[j];
                for (int o = 32; o > 0; o >>= 1) acc += __shfl_down(acc, o, 64);
                if (lane == 0) qb[b] = acc;
            }
        }
        return;
    }
    int hblk = blockIdx.x & 7, pc = blockIdx.x >> 3;
    int h = hblk * 256 + threadIdx.x;
    float acc[B];
#pragma unroll
    for (int b = 0; b < B; ++b) acc[b] = 0.f;
#pragma unroll 4
    for (int p = pc * 32; p < pc * 32 + 32; ++p) {
        float w = Wk[(size_t)p * H + h];
#pragma unroll
        for (int b = 0; b < B; ++b) acc[b] += qv[b * PROJ + p] * w;
    }
#pragma unroll
    for (int b = 0; b < B; ++b)
        pqk[((size_t)(pc * B + b)) * H + h] = acc[b];
}

// K4b: reduce 16 p-chunks.  grid = 64
__global__ void __launch_bounds__(256) k_qk_finish(const float* __restrict__ pqk,
                                                   float* __restrict__ qk) {
    int idx = blockIdx.x * 256 + threadIdx.x;  // b*H + h
    int b = idx >> 11, h = idx & 2047;
    float s = 0.f;
#pragma unroll 8
    for (int pc = 0; pc < 16; ++pc) s += pqk[((size_t)(pc * B + b)) * H + h];
    qk[idx] = s;
}

// K5: the big streaming pass.  scores[b,n] = conf[n] * (keys[n].qk[b] + qb[b])
// block = 512 threads (8 waves), each wave does 4 rows -> 32 rows/block.
// grid = 100000/32 = 3125 exactly.
// vfloat2 accumulators -> v_pk_fma_f32 (2 FMA/inst) halves VALU issue
// pressure; unroll capped at 2 (full unroll spilled ~1 GB in round 1).
__global__ void __launch_bounds__(512) k_scores(const float* __restrict__ keys,
                                                const float* __restrict__ conf,
                                                const float* __restrict__ qk,
                                                const float* __restrict__ qb,
                                                float* __restrict__ scores) {
    __shared__ float sqk[B * H];  // 64 KB
    for (int i = threadIdx.x * 4; i < B * H; i += 2048)
        *(vfloat4*)(sqk + i) = *(const vfloat4*)(qk + i);
    __syncthreads();

    const int wave = threadIdx.x >> 6, lane = threadIdx.x & 63;
    const long r0 = (long)blockIdx.x * 32 + wave * 4;

    vfloat2 acc[4][B];
#pragma unroll
    for (int r = 0; r < 4; ++r)
#pragma unroll
        for (int b = 0; b < B; ++b) acc[r][b] = (vfloat2){0.f, 0.f};

#pragma unroll 2
    for (int it = 0; it < 8; ++it) {
        int j = it * 256 + lane * 4;
        vfloat4 kv[4];
#pragma unroll
        for (int r = 0; r < 4; ++r)
            kv[r] = __builtin_nontemporal_load(
                (const vfloat4*)(keys + (size_t)(r0 + r) * H + j));
#pragma unroll
        for (int b = 0; b < B; ++b) {
            vfloat4 w = *(const vfloat4*)(sqk + b * H + j);
            vfloat2 wlo = w.xy, whi = w.zw;
#pragma unroll
            for (int r = 0; r < 4; ++r) {
                acc[r][b] += kv[r].xy * wlo;
                acc[r][b] += kv[r].zw * whi;
            }
        }
    }

#pragma unroll
    for (int r = 0; r < 4; ++r) {
        long n = r0 + r;
#pragma unroll
        for (int b = 0; b < B; ++b) {
            float v = acc[r][b].x + acc[r][b].y;
            for (int o = 32; o > 0; o >>= 1) v += __shfl_down(v, o, 64);
            if (lane == 0)
                scores[(size_t)b * NK + n] = conf[n] * (v + qb[b]);
        }
    }
}

// ---------------------------------------------------------------------------
// Top-k, two-stage.  Stage 1: grid = B*NCHUNK = 512 blocks x 256 threads.
// Each block -> top-10 of its 1600-element chunk via per-thread sorted top-10
// + per-wave shuffle argmax-consume + cross-wave merge (wave 0).
__global__ void __launch_bounds__(256) k_topk1(const float* __restrict__ scores,
                                               float* __restrict__ candv,
                                               int* __restrict__ candi) {
    const int c = blockIdx.x & (NCHUNK - 1), b = blockIdx.x >> 6;
    const int tid = threadIdx.x, lane = tid & 63, wave = tid >> 6;
    __shared__ float wv[4 * TOPK];
    __shared__ int   wi[4 * TOPK];

    float lv[TOPK];
    int   li[TOPK];
#pragma unroll
    for (int i = 0; i < TOPK; ++i) { lv[i] = NEG_INF; li[i] = 0; }

    const int start = c * CS;
    const int end = (start + CS < NK) ? start + CS : NK;
    for (int n = start + tid; n < end; n += 256) {
        float v = scores[(size_t)b * NK + n];
        if (v > lv[TOPK - 1]) {
            bool m[TOPK];
#pragma unroll
            for (int i = 0; i < TOPK; ++i) m[i] = (lv[i] < v);
#pragma unroll
            for (int i = TOPK - 1; i > 0; --i)
                if (m[i - 1]) { lv[i] = lv[i - 1]; li[i] = li[i - 1]; }
#pragma unroll
            for (int i = 0; i < TOPK; ++i)
                if (m[i] && (i == 0 || !m[i - 1])) { lv[i] = v; li[i] = n; }
        }
    }

    // per-wave argmax-consume: lists are sorted desc, so each lane proposes
    // its current head; winner advances its pointer.
    int ptr = 0;
    for (int round = 0; round < TOPK; ++round) {
        float bv = (ptr < TOPK) ? lv[ptr] : NEG_INF;
        int   bi = (ptr < TOPK) ? li[ptr] : 0;
        int   bl = lane;
        for (int o = 32; o > 0; o >>= 1) {
            float ov = __shfl_down(bv, o, 64);
            int   oi = __shfl_down(bi, o, 64);
            int   ol = __shfl_down(bl, o, 64);
            if (ov > bv) { bv = ov; bi = oi; bl = ol; }
        }
        if (lane == 0) { wv[wave * TOPK + round] = bv; wi[wave * TOPK + round] = bi; }
        bl = __shfl(bl, 0, 64);
        if (lane == bl) ptr++;
    }
    __syncthreads();

    // wave 0 merges the 4 waves' top-10 lists (40 candidates, 1 per lane)
    if (wave == 0) {
        float v = (lane < 4 * TOPK) ? wv[lane] : NEG_INF;
        int  id = (lane < 4 * TOPK) ? wi[lane] : 0;
        for (int round = 0; round < TOPK; ++round) {
            float bv = v; int bi = id; int bl = lane;
            for (int o = 32; o > 0; o >>= 1) {
                float ov = __shfl_down(bv, o, 64);
                int   oi = __shfl_down(bi, o, 64);
                int   ol = __shfl_down(bl, o, 64);
                if (ov > bv) { bv = ov; bi = oi; bl = ol; }
            }
            if (lane == 0) {
                candv[(size_t)(b * NCHUNK + c) * TOPK + round] = bv;
                candi[(size_t)(b * NCHUNK + c) * TOPK + round] = bi;
            }
            bl = __shfl(bl, 0, 64);
            if (lane == bl) v = NEG_INF;
        }
    }
}

// K7: stage-2 top-k merge (redundant per block, wave 0) + mem_summary ->
// second half of gate_input.  grid = 64 blocks x 256 threads.
__global__ void __launch_bounds__(256) k_memsum(const float* __restrict__ keys,
                                                const float* __restrict__ candv,
                                                const int* __restrict__ candi,
                                                float* __restrict__ gi) {
    const int blk = blockIdx.x;
    const int b = (blk * 256) >> 11;  // 8 consecutive blocks per batch
    const int tid = threadIdx.x, lane = tid & 63, wave = tid >> 6;
    __shared__ int stop[TOPK];

    // wave 0: merge the 640 stage-1 candidates (lane <-> chunk, sorted desc)
    if (wave == 0) {
        float lv[TOPK];
        int   li[TOPK];
#pragma unroll
        for (int r = 0; r < TOPK; ++r) {
            lv[r] = candv[(size_t)(b * NCHUNK + lane) * TOPK + r];
            li[r] = candi[(size_t)(b * NCHUNK + lane) * TOPK + r];
        }
        int ptr = 0;
        for (int round = 0; round < TOPK; ++round) {
            float bv = (ptr < TOPK) ? lv[ptr] : NEG_INF;
            int   bi = (ptr < TOPK) ? li[ptr] : 0;
            int   bl = lane;
            for (int o = 32; o > 0; o >>= 1) {
                float ov = __shfl_down(bv, o, 64);
                int   oi = __shfl_down(bi, o, 64);
                int   ol = __shfl_down(bl, o, 64);
                if (ov > bv) { bv = ov; bi = oi; bl = ol; }
            }
            if (lane == 0) stop[round] = bi;
            bl = __shfl(bl, 0, 64);
            if (lane == bl) ptr++;
        }
    }
    __syncthreads();

    int h = (blk * 256 + tid) & 2047;
    float s = 0.f;
#pragma unroll
    for (int i = 0; i < TOPK; ++i) {
        int n = stop[i];
        s += keys[(size_t)n * H + h];
    }
    gi[(size_t)b * 2 * H + H + h] = s * (1.0f / TOPK);
}

// K8: gate = sigmoid(gi @ Wg.T + bg), h1 = gelu(gi @ Wm1.T + bm1)
// One wave per output row across both matrices (rows 0..2047 -> gate,
// 2048..4095 -> h1), all 8 batches per wave.  grid = 4096/4 = 1024
// NOTE: unroll capped at 2 — a full unroll hoists 16 its x 9 float4 loads
// (~576 VGPRs) -> mass scratch spill (round-1 k_scores signature).
__global__ void __launch_bounds__(256) k_mlp1(const float* __restrict__ gi,
                                              const float* __restrict__ Wg,
                                              const float* __restrict__ bg,
                                              const float* __restrict__ Wm1,
                                              const float* __restrict__ bm1,
                                              float* __restrict__ gate,
                                              float* __restrict__ h1) {
    int wave = threadIdx.x >> 6, lane = threadIdx.x & 63;
    int row = blockIdx.x * 4 + wave;  // 0..4095
    bool isGate = row < H;
    int i = isGate ? row : row - H;
    const float* W = (isGate ? Wg : Wm1) + (size_t)i * 2 * H;

    float acc[B];
#pragma unroll
    for (int b = 0; b < B; ++b) acc[b] = 0.f;

#pragma unroll 2
    for (int j = lane * 4; j < 2 * H; j += 256) {
        float4 w = *(const float4*)(W + j);
#pragma unroll
        for (int b = 0; b < B; ++b) {
            float4 g = *(const float4*)(gi + (size_t)b * 2 * H + j);
            acc[b] += w.x * g.x + w.y * g.y + w.z * g.z + w.w * g.w;
        }
    }
#pragma unroll
    for (int b = 0; b < B; ++b) {
        float v = acc[b];
        for (int o = 32; o > 0; o >>= 1) v += __shfl_down(v, o, 64);
        if (lane == 0) {
            if (isGate) {
                v += bg[i];
                gate[b * H + i] = 1.0f / (1.0f + expf(-v));
            } else {
                v += bm1[i];
                h1[b * H + i] = 0.5f * v * (1.0f + erff(v * 0.70710678118654752f));
            }
        }
    }
}

// K9: mem_integrated = h1 @ Wm2.T + bm2; gm = gate * mem_integrated.
// grid = 2048/4 = 512.  unroll capped at 2 (spill avoidance, see k_mlp1).
__global__ void __launch_bounds__(256) k_mlp2(const float* __restrict__ h1,
                                              const float* __restrict__ Wm2,
                                              const float* __restrict__ bm2,
                                              const float* __restrict__ gate,
                                              float* __restrict__ gm) {
    int wave = threadIdx.x >> 6, lane = threadIdx.x & 63;
    int o = blockIdx.x * 4 + wave;  // 0..2047
    const float* W = Wm2 + (size_t)o * H;
    float acc[B];
#pragma unroll
    for (int b = 0; b < B; ++b) acc[b] = 0.f;
#pragma unroll 2
    for (int j = lane * 4; j < H; j += 256) {
        float4 w = *(const float4*)(W + j);
#pragma unroll
        for (int b = 0; b < B; ++b) {
            float4 hh = *(const float4*)(h1 + (size_t)b * H + j);
            acc[b] += w.x * hh.x + w.y * hh.y + w.z * hh.z + w.w * hh.w;
        }
    }
#pragma unroll
    for (int b = 0; b < B; ++b) {
        float v = acc[b];
        for (int oo = 32; oo > 0; oo >>= 1) v += __shfl_down(v, oo, 64);
        if (lane == 0) gm[b * H + o] = gate[b * H + o] * (v + bm2[o]);
    }
}

// K10: y = x + gm (broadcast over T), LayerNorm over H.
// One wave per row, whole row in registers, xor-butterfly reductions:
// zero barriers, zero LDS.  x read is cached (should hit L3, warmed by K1).
// grid = B*T/4 = 4096, block = 256.
__global__ void __launch_bounds__(256) k_final(const float* __restrict__ x,
                                               const float* __restrict__ gm,
                                               const float* __restrict__ gamma,
                                               const float* __restrict__ beta,
                                               float* __restrict__ out) {
    const int lane = threadIdx.x & 63, wave = threadIdx.x >> 6;
    const size_t row = (size_t)blockIdx.x * 4 + wave;
    const int b = (int)(row >> 11);  // T = 2048
    const float* xr  = x + row * H;
    const float* gmr = gm + (size_t)b * H;

    vfloat4 y[8];
    float s = 0.f;
#pragma unroll
    for (int it = 0; it < 8; ++it) {
        int j = it * 256 + lane * 4;
        vfloat4 xv = *(const vfloat4*)(xr + j);
        vfloat4 gv = *(const vfloat4*)(gmr + j);
        y[it] = xv + gv;
        s += y[it].x + y[it].y + y[it].z + y[it].w;
    }
#pragma unroll
    for (int o = 32; o > 0; o >>= 1) s += __shfl_xor(s, o, 64);
    const float mu = s * (1.0f / H);

    float s2 = 0.f;
#pragma unroll
    for (int it = 0; it < 8; ++it) {
        vfloat4 d = y[it] - mu;
        y[it] = d;
        s2 += d.x * d.x + d.y * d.y + d.z * d.z + d.w * d.w;
    }
#pragma unroll
    for (int o = 32; o > 0; o >>= 1) s2 += __shfl_xor(s2, o, 64);
    const float inv = rsqrtf(s2 * (1.0f / H) + 1e-5f);

#pragma unroll
    for (int it = 0; it < 8; ++it) {
        int j = it * 256 + lane * 4;
        vfloat4 g = *(const vfloat4*)(gamma + j);
        vfloat4 bb = *(const vfloat4*)(beta + j);
        vfloat4 o_ = y[it] * inv * g + bb;
        __builtin_nontemporal_store(o_, (vfloat4*)(out + row * H + j));
    }
}

// ---------------------------------------------------------------------------
extern "C" void kernel_launch(void* const* d_in, const int* in_sizes, int n_in,
                              void* d_out, int out_size, void* d_ws, size_t ws_size,
                              hipStream_t stream) {
    const float* x     = (const float*)d_in[0];
    const float* keys  = (const float*)d_in[1];
    const float* conf  = (const float*)d_in[2];
    const float* Wq    = (const float*)d_in[3];
    const float* bq    = (const float*)d_in[4];
    const float* Wk    = (const float*)d_in[5];
    const float* bk    = (const float*)d_in[6];
    const float* Wg    = (const float*)d_in[7];
    const float* bg    = (const float*)d_in[8];
    const float* Wm1   = (const float*)d_in[9];
    const float* bm1   = (const float*)d_in[10];
    const float* Wm2   = (const float*)d_in[11];
    const float* bm2   = (const float*)d_in[12];
    const float* gamma = (const float*)d_in[13];
    const float* beta  = (const float*)d_in[14];
    float* out = (float*)d_out;

    float* ws = (float*)d_ws;
    float* partial = ws;        ws += (size_t)B * TCHUNK * H;  // 1M floats
    float* query   = ws;        ws += B * H;
    float* gi      = ws;        ws += B * 2 * H;
    float* qv      = ws;        ws += B * PROJ;
    float* qb      = ws;        ws += 64;
    float* pqk     = ws;        ws += 16 * B * H;
    float* qk      = ws;        ws += B * H;
    float* scores  = ws;        ws += (size_t)B * NK;          // 800000
    float* candv   = ws;        ws += B * NCHUNK * TOPK;       // 5120
    int*   candi   = (int*)ws;  ws += B * NCHUNK * TOPK;       // 5120
    float* gate    = ws;        ws += B * H;
    float* h1      = ws;        ws += B * H;
    float* gm      = ws;        ws += B * H;

    k_partial_sum<<<B * TCHUNK * 2, 256, 0, stream>>>(x, partial);
    k_finish_mean<<<B * H / 256, 256, 0, stream>>>(partial, query, gi);
    k_q<<<B * PROJ / 4, 256, 0, stream>>>(query, Wq, bq, qv);
    k_qk_partial<<<129, 256, 0, stream>>>(qv, Wk, bk, pqk, qb);
    k_qk_finish<<<B * H / 256, 256, 0, stream>>>(pqk, qk);
    k_scores<<<NK / 32, 512, 0, stream>>>(keys, conf, qk, qb, scores);
    k_topk1<<<B * NCHUNK, 256, 0, stream>>>(scores, candv, candi);
    k_memsum<<<B * H / 256, 256, 0, stream>>>(keys, candv, candi, gi);
    k_mlp1<<<2 * H / 4, 256, 0, stream>>>(gi, Wg, bg, Wm1, bm1, gate, h1);
    k_mlp2<<<H / 4, 256, 0, stream>>>(h1, Wm2, bm2, gate, gm);
    k_final<<<B * T / 4, 256, 0, stream>>>(x, gm, gamma, beta, out);
}